// Round 4
// baseline (48.268 us; speedup 1.0000x reference)
//
#include <hip/hip_runtime.h>

typedef float float4v __attribute__((ext_vector_type(4)));

#define TL 16   // l-strip per thread (16 -> 2048 blocks -> 32 waves/CU)
#define K  4

__global__ __launch_bounds__(256) void cconv_kernel(
    const float* __restrict__ x,
    const float* __restrict__ w,
    const float* __restrict__ bias,
    float* __restrict__ y,
    int B, int L, int D)
{
    const int DG = D >> 2;             // d-groups of 4 (float4)
    const int NT = L / TL;             // l-tiles per batch
    int tid  = blockIdx.x * blockDim.x + threadIdx.x;
    int dg   = tid % DG;               // consecutive threads -> consecutive float4 (coalesced)
    int rest = tid / DG;
    int lt   = rest % NT;
    int b    = rest / NT;
    if (b >= B) return;

    const int d0 = dg << 2;

    // ---- weights: w[(d0+j)*K + k], 16 contiguous floats ----
    float wv[K][4];
    {
        const float4v* wp = reinterpret_cast<const float4v*>(w + (size_t)d0 * K);
        #pragma unroll
        for (int j = 0; j < 4; ++j) {
            float4v v = wp[j];         // w[(d0+j)*K + 0..3]
            #pragma unroll
            for (int k = 0; k < K; ++k) wv[k][j] = v[k];
        }
    }
    float4v bv = *reinterpret_cast<const float4v*>(bias + d0);

    // ---- sliding window over l ----
    const int    l0   = lt * TL;
    const size_t base = (size_t)b * L * D + d0;

    float4v xm3 = {0.f, 0.f, 0.f, 0.f};
    float4v xm2 = {0.f, 0.f, 0.f, 0.f};
    float4v xm1 = {0.f, 0.f, 0.f, 0.f};

    if (l0 >= 3) {
        xm3 = *reinterpret_cast<const float4v*>(x + base + (size_t)(l0 - 3) * D);
        xm2 = *reinterpret_cast<const float4v*>(x + base + (size_t)(l0 - 2) * D);
        xm1 = *reinterpret_cast<const float4v*>(x + base + (size_t)(l0 - 1) * D);
    }

    #pragma unroll
    for (int t = 0; t < TL; ++t) {
        const int l = l0 + t;
        float4v xc = *reinterpret_cast<const float4v*>(x + base + (size_t)l * D);

        float4v out;
        #pragma unroll
        for (int j = 0; j < 4; ++j) {
            float acc = bv[j];
            acc = fmaf(wv[0][j], xm3[j], acc);
            acc = fmaf(wv[1][j], xm2[j], acc);
            acc = fmaf(wv[2][j], xm1[j], acc);
            acc = fmaf(wv[3][j], xc[j],  acc);
            out[j] = acc;
        }
        __builtin_nontemporal_store(out,
            reinterpret_cast<float4v*>(y + base + (size_t)l * D));

        xm3 = xm2; xm2 = xm1; xm1 = xc;
    }
}

extern "C" void kernel_launch(void* const* d_in, const int* in_sizes, int n_in,
                              void* d_out, int out_size, void* d_ws, size_t ws_size,
                              hipStream_t stream) {
    const float* x  = (const float*)d_in[0];
    const float* w  = (const float*)d_in[1];
    const float* bb = (const float*)d_in[2];
    float* y        = (float*)d_out;

    const int D = in_sizes[2];          // 1024
    const int L = 4096;
    const int B = in_sizes[0] / (L * D);

    const int threads = B * (L / TL) * (D / 4);
    const int block   = 256;
    const int grid    = (threads + block - 1) / block;

    cconv_kernel<<<grid, block, 0, stream>>>(x, w, bb, y, B, L, D);
}

// Round 5
// 44.270 us; speedup vs baseline: 1.0903x; 1.0903x over previous
//
#include <hip/hip_runtime.h>

typedef float float2v __attribute__((ext_vector_type(2)));
typedef float float4v __attribute__((ext_vector_type(4)));

#define TL   64   // l-strip per thread: halo fraction 3/64 ≈ 4.7%
#define K    4
#define NXCD 8

__global__ __launch_bounds__(256) void cconv_kernel(
    const float* __restrict__ x,
    const float* __restrict__ w,
    const float* __restrict__ bias,
    float* __restrict__ y,
    int B, int L, int D, int cpx)
{
    // XCD-aware swizzle (T1): hardware round-robins consecutive blockIdx
    // across the 8 XCDs; remap so each XCD owns a CONTIGUOUS chunk of the
    // logical grid -> adjacent-lt blocks (which share 3 halo rows) land on
    // the same XCD's L2. Bijective since gridDim.x % 8 == 0.
    const int blk = (int)(blockIdx.x % NXCD) * cpx + (int)(blockIdx.x / NXCD);

    const int DG = D >> 1;             // d-groups of 2 (float2, 8 B/lane)
    const int NT = L / TL;             // l-tiles per batch
    int tid  = blk * (int)blockDim.x + (int)threadIdx.x;
    int dg   = tid % DG;               // consecutive lanes -> consecutive float2 (coalesced)
    int rest = tid / DG;
    int lt   = rest % NT;
    int b    = rest / NT;
    if (b >= B) return;

    const int d0 = dg << 1;

    // ---- weights: w[(d0+j)*K + k], 8 contiguous floats ----
    float wv[K][2];
    {
        #pragma unroll
        for (int j = 0; j < 2; ++j) {
            float4v v = *reinterpret_cast<const float4v*>(w + (size_t)(d0 + j) * K);
            #pragma unroll
            for (int k = 0; k < K; ++k) wv[k][j] = v[k];
        }
    }
    float2v bv = *reinterpret_cast<const float2v*>(bias + d0);

    // ---- sliding window over l ----
    const int    l0   = lt * TL;
    const size_t base = (size_t)b * L * D + d0;

    float2v xm3 = {0.f, 0.f};
    float2v xm2 = {0.f, 0.f};
    float2v xm1 = {0.f, 0.f};

    if (l0 >= 3) {
        xm3 = *reinterpret_cast<const float2v*>(x + base + (size_t)(l0 - 3) * D);
        xm2 = *reinterpret_cast<const float2v*>(x + base + (size_t)(l0 - 2) * D);
        xm1 = *reinterpret_cast<const float2v*>(x + base + (size_t)(l0 - 1) * D);
    }

    #pragma unroll 8
    for (int t = 0; t < TL; ++t) {
        const int l = l0 + t;
        float2v xc = *reinterpret_cast<const float2v*>(x + base + (size_t)l * D);

        float2v out;
        #pragma unroll
        for (int j = 0; j < 2; ++j) {
            float acc = bv[j];
            acc = fmaf(wv[0][j], xm3[j], acc);
            acc = fmaf(wv[1][j], xm2[j], acc);
            acc = fmaf(wv[2][j], xm1[j], acc);
            acc = fmaf(wv[3][j], xc[j],  acc);
            out[j] = acc;
        }
        __builtin_nontemporal_store(out,
            reinterpret_cast<float2v*>(y + base + (size_t)l * D));

        xm3 = xm2; xm2 = xm1; xm1 = xc;
    }
}

extern "C" void kernel_launch(void* const* d_in, const int* in_sizes, int n_in,
                              void* d_out, int out_size, void* d_ws, size_t ws_size,
                              hipStream_t stream) {
    const float* x  = (const float*)d_in[0];
    const float* w  = (const float*)d_in[1];
    const float* bb = (const float*)d_in[2];
    float* y        = (float*)d_out;

    const int D = in_sizes[2];          // 1024
    const int L = 4096;
    const int B = in_sizes[0] / (L * D);

    const int threads = B * (L / TL) * (D / 2);
    const int block   = 256;
    const int grid    = (threads + block - 1) / block;  // 1024, divisible by 8
    const int cpx     = grid / NXCD;

    cconv_kernel<<<grid, block, 0, stream>>>(x, w, bb, y, B, L, D, cpx);
}